// Round 14
// baseline (6909.590 us; speedup 1.0000x reference)
//
#include <hip/hip_runtime.h>

#define BB 64
#define TT 2048
#define FF 15
#define UU 256
#define N3 768

typedef _Float16 half8 __attribute__((ext_vector_type(8)));
typedef float f32x4 __attribute__((ext_vector_type(4)));

__device__ _Float16 g_seq1[BB * TT * UU];       // 67 MB (f16)
__device__ float g_xp[(size_t)BB * TT * N3];    // 402 MB (f32)
__device__ uint4 g_U1p[48 * 8 * 64];            // 48 n-tiles x 8 k-tiles x 64 lanes x 16B
__device__ uint4 g_U2p[48 * 8 * 64];
__device__ uint4 g_W2p[48 * 8 * 64];

// Pack a 256x768 fp32 matrix into per-lane MFMA B-fragments (f16).
// Fragment (nt, kt), lane l, dword d holds {M[kt*32+8*(l>>4)+2d][nt*16+(l&15)],
// M[...+2d+1][...]}. k-mapping f(l,i)=8*(l>>4)+i matches the A-side builds.
__global__ __launch_bounds__(256) void prep_upk(const float* __restrict__ U,
                                                unsigned* __restrict__ Up) {
    int idx = blockIdx.x * 256 + threadIdx.x;    // 0 .. 98303
    int d = idx & 3, l = (idx >> 2) & 63, kt = (idx >> 8) & 7, nt = idx >> 11;
    int row = kt * 32 + ((l >> 4) << 3) + 2 * d;
    int col = nt * 16 + (l & 15);
    unsigned short lo = __builtin_bit_cast(unsigned short, (_Float16)U[row * N3 + col]);
    unsigned short hi = __builtin_bit_cast(unsigned short, (_Float16)U[(row + 1) * N3 + col]);
    Up[idx] = (unsigned)lo | ((unsigned)hi << 16);
}

// xp1 = x @ W1 + b_in (+ b_rec folded for z,r columns)   (K=15, memory-bound)
__global__ __launch_bounds__(256) void gemm_k15(
    const float* __restrict__ x, const float* __restrict__ W1,
    const float* __restrict__ bin, const float* __restrict__ brec,
    float* __restrict__ C) {
    __shared__ float xr[8][FF];
    const int m0 = blockIdx.x * 8;
    const int j  = blockIdx.y * 256 + threadIdx.x;
    if (threadIdx.x < 8 * FF) {
        int r = threadIdx.x / FF, k = threadIdx.x - r * FF;
        xr[r][k] = x[(size_t)(m0 + r) * FF + k];
    }
    __syncthreads();
    float wv[FF];
#pragma unroll
    for (int k = 0; k < FF; k++) wv[k] = W1[k * N3 + j];
    const float bj = bin[j] + (j < 2 * UU ? brec[j] : 0.f);
#pragma unroll
    for (int r = 0; r < 8; r++) {
        float a = bj;
#pragma unroll
        for (int k = 0; k < FF; k++) a += xr[r][k] * wv[k];
        C[(size_t)(m0 + r) * N3 + j] = a;
    }
}

// xp2 = seq1 @ W2 + b_in (+ b_rec folded for z,r)  via f16 MFMA.
__global__ __launch_bounds__(512) void gemm_xp_mfma(
    const _Float16* __restrict__ A, const uint4* __restrict__ Wp,
    const float* __restrict__ bin, const float* __restrict__ brec,
    float* __restrict__ C) {
    const int tid = threadIdx.x, w = tid >> 6, lane = tid & 63;
    const int mt = w >> 1;
    const int nb = (w & 1) * 24;
    const int arow = blockIdx.x * 64 + mt * 16 + (lane & 15);
    const int ko   = (lane >> 4) * 8;

    f32x4 acc[24] = {};
    const _Float16* ap = A + (size_t)arow * 256 + ko;

#pragma unroll
    for (int kt = 0; kt < 8; kt++) {
        half8 av = *(const half8*)(ap + kt * 32);
        const uint4* wp = Wp + (size_t)(nb * 8 + kt) * 64 + lane;
#pragma unroll
        for (int n = 0; n < 24; n++) {
            half8 bf = __builtin_bit_cast(half8, wp[(size_t)n * 8 * 64]);
            acc[n] = __builtin_amdgcn_mfma_f32_16x16x32_f16(av, bf, acc[n], 0, 0, 0);
        }
    }
    const int rbase = blockIdx.x * 64 + mt * 16 + (lane >> 4) * 4;
#pragma unroll
    for (int n = 0; n < 24; n++) {
        int col = (nb + n) * 16 + (lane & 15);
        float bv = bin[col] + (col < 2 * UU ? brec[col] : 0.f);
#pragma unroll
        for (int d = 0; d < 4; d++)
            C[(size_t)(rbase + d) * N3 + col] = acc[n][d] + bv;
    }
}

// ---------------- GRU recurrence: 16 waves x 3 n-tiles (r13) + tail shave ----
// r14 changes vs r13 (register structure untouched):
//  (1) last 2 k-tiles issue gate-sequenced (a0,a0,a1,a1,a2,a2) so the z
//      accumulator finishes ~4 MFMA slots early and its exp overlaps the
//      remaining MFMA issue; r's exp overlaps the last two; hh (no exp) is
//      the only true tail. kt=0..5 keep the r13 interleave (dep-distance 3).
//  (2) seq_out global store moved after the barrier (out of the pre-barrier
//      vmcnt drain).
__global__ __launch_bounds__(1024) __attribute__((amdgpu_waves_per_eu(4, 4)))
void gru_mfma16(const uint4* __restrict__ Up, const float* __restrict__ brec,
                const float* __restrict__ xp, _Float16* __restrict__ seq_out,
                float* __restrict__ state_out, float* __restrict__ extra_out) {
    const int b = blockIdx.x, tid = threadIdx.x;
    const int w = tid >> 6, lane = tid & 63;
    const int l15 = lane & 15;
    const int uA = 16 * w + l15;                   // this wave's unit range

    __shared__ __align__(16) _Float16 h2s[2][UU];

    // 24 B-fragments: z-tile w, r-tile 16+w, hh-tile 32+w, 8 k-tiles each
    half8 ub[24];
#pragma unroll
    for (int kt = 0; kt < 8; kt++) {
        ub[0 * 8 + kt] = __builtin_bit_cast(half8, Up[((w)      * 8 + kt) * 64 + lane]);
        ub[1 * 8 + kt] = __builtin_bit_cast(half8, Up[((16 + w) * 8 + kt) * 64 + lane]);
        ub[2 * 8 + kt] = __builtin_bit_cast(half8, Up[((32 + w) * 8 + kt) * 64 + lane]);
    }
    const float brh = brec[uA + 2 * UU];

    if (tid < 128) ((unsigned*)h2s[0])[tid] = 0u;
    float h = 0.f;
    __syncthreads();

    const float* __restrict__ xpb = xp + (size_t)b * TT * N3;
    float xz = xpb[uA], xr = xpb[uA + UU], xh = xpb[uA + 2 * UU];

    const int arow = (lane >> 4) << 3;

    for (int t = 0; t < TT; t++) {
        const float* xn = xpb + (size_t)(t + 1 < TT ? t + 1 : t) * N3;
        float xzn = xn[uA], xrn = xn[uA + UU], xhn = xn[uA + 2 * UU];

        const _Float16* hcur = h2s[t & 1];
        f32x4 a0 = {0.f, 0.f, 0.f, 0.f}, a1 = a0, a2 = a0;
#pragma unroll
        for (int kt = 0; kt < 6; kt++) {
            half8 av = *(const half8*)&hcur[kt * 32 + arow];
            a0 = __builtin_amdgcn_mfma_f32_16x16x32_f16(av, ub[0 * 8 + kt], a0, 0, 0, 0);
            a1 = __builtin_amdgcn_mfma_f32_16x16x32_f16(av, ub[1 * 8 + kt], a1, 0, 0, 0);
            a2 = __builtin_amdgcn_mfma_f32_16x16x32_f16(av, ub[2 * 8 + kt], a2, 0, 0, 0);
        }
        // gate-sequenced tail: finish z first (longest post-op), then r, then hh
        {
            half8 av6 = *(const half8*)&hcur[6 * 32 + arow];
            half8 av7 = *(const half8*)&hcur[7 * 32 + arow];
            a0 = __builtin_amdgcn_mfma_f32_16x16x32_f16(av6, ub[0 * 8 + 6], a0, 0, 0, 0);
            a0 = __builtin_amdgcn_mfma_f32_16x16x32_f16(av7, ub[0 * 8 + 7], a0, 0, 0, 0);
            a1 = __builtin_amdgcn_mfma_f32_16x16x32_f16(av6, ub[1 * 8 + 6], a1, 0, 0, 0);
            a1 = __builtin_amdgcn_mfma_f32_16x16x32_f16(av7, ub[1 * 8 + 7], a1, 0, 0, 0);
            a2 = __builtin_amdgcn_mfma_f32_16x16x32_f16(av6, ub[2 * 8 + 6], a2, 0, 0, 0);
            a2 = __builtin_amdgcn_mfma_f32_16x16x32_f16(av7, ub[2 * 8 + 7], a2, 0, 0, 0);
        }

        // gates (brz/brr pre-folded into xz/xr by the producer GEMM)
        float z  = 1.f / (1.f + __expf(-(xz + a0[0])));
        float r  = 1.f / (1.f + __expf(-(xr + a1[0])));
        float hh = xh + r * (a2[0] + brh);
        hh = hh > 0.f ? hh : 0.f;
        h = z * h + (1.f - z) * hh;

        _Float16* hnxt = h2s[(t + 1) & 1];
        _Float16 hq = (_Float16)h;
        if (lane < 16) hnxt[uA] = hq;
        __syncthreads();
        if (seq_out && lane < 16)
            seq_out[(size_t)b * TT * UU + (size_t)t * UU + uA] = hq;
        xz = xzn; xr = xrn; xh = xhn;
    }

    if (lane < 16) {
        state_out[b * UU + uA] = h;
        if (extra_out) extra_out[b * UU + uA] = h;
    }
}

extern "C" void kernel_launch(void* const* d_in, const int* in_sizes, int n_in,
                              void* d_out, int out_size, void* d_ws, size_t ws_size,
                              hipStream_t stream) {
    const float* x  = (const float*)d_in[0];
    const float* W1 = (const float*)d_in[1];
    const float* U1 = (const float*)d_in[2];
    const float* b1 = (const float*)d_in[3];
    const float* W2 = (const float*)d_in[4];
    const float* U2 = (const float*)d_in[5];
    const float* b2 = (const float*)d_in[6];
    float* out = (float*)d_out;

    uint4* U1p; hipGetSymbolAddress((void**)&U1p, HIP_SYMBOL(g_U1p));
    uint4* U2p; hipGetSymbolAddress((void**)&U2p, HIP_SYMBOL(g_U2p));
    uint4* W2p; hipGetSymbolAddress((void**)&W2p, HIP_SYMBOL(g_W2p));
    _Float16* seq1; hipGetSymbolAddress((void**)&seq1, HIP_SYMBOL(g_seq1));
    float* xp;      hipGetSymbolAddress((void**)&xp,   HIP_SYMBOL(g_xp));

    prep_upk<<<384, 256, 0, stream>>>(U1, (unsigned*)U1p);
    prep_upk<<<384, 256, 0, stream>>>(U2, (unsigned*)U2p);
    prep_upk<<<384, 256, 0, stream>>>(W2, (unsigned*)W2p);

    // layer 1 (b_rec z/r folded into xp by gemm_k15)
    gemm_k15<<<dim3(BB * TT / 8, 3), 256, 0, stream>>>(x, W1, b1, b1 + N3, xp);
    gru_mfma16<<<BB, 1024, 0, stream>>>(U1p, b1 + N3, xp, seq1, out + BB * UU, nullptr);

    // layer 2 (b_rec z/r folded into xp by gemm_xp_mfma)
    gemm_xp_mfma<<<BB * TT / 64, 512, 0, stream>>>(seq1, W2p, b2, b2 + N3, xp);
    gru_mfma16<<<BB, 1024, 0, stream>>>(U2p, b2 + N3, xp, nullptr, out + 2 * BB * UU, out);
}

// Round 15
// 4488.616 us; speedup vs baseline: 1.5394x; 1.5394x over previous
//
#include <hip/hip_runtime.h>

#define BB 64
#define TT 2048
#define FF 15
#define UU 256
#define N3 768

typedef _Float16 half8 __attribute__((ext_vector_type(8)));
typedef float f32x4 __attribute__((ext_vector_type(4)));

__device__ _Float16 g_seq1[BB * TT * UU];       // 67 MB (f16)
__device__ float g_xp[(size_t)BB * TT * N3];    // 402 MB (f32)
__device__ uint4 g_U1p[48 * 8 * 64];            // 48 n-tiles x 8 k-tiles x 64 lanes x 16B
__device__ uint4 g_U2p[48 * 8 * 64];
__device__ uint4 g_W2p[48 * 8 * 64];

// Pack a 256x768 fp32 matrix into per-lane MFMA B-fragments (f16).
// Fragment (nt, kt), lane l, dword d holds {M[kt*32+8*(l>>4)+2d][nt*16+(l&15)],
// M[...+2d+1][...]}. k-mapping f(l,i)=8*(l>>4)+i matches the A-side builds.
__global__ __launch_bounds__(256) void prep_upk(const float* __restrict__ U,
                                                unsigned* __restrict__ Up) {
    int idx = blockIdx.x * 256 + threadIdx.x;    // 0 .. 98303
    int d = idx & 3, l = (idx >> 2) & 63, kt = (idx >> 8) & 7, nt = idx >> 11;
    int row = kt * 32 + ((l >> 4) << 3) + 2 * d;
    int col = nt * 16 + (l & 15);
    unsigned short lo = __builtin_bit_cast(unsigned short, (_Float16)U[row * N3 + col]);
    unsigned short hi = __builtin_bit_cast(unsigned short, (_Float16)U[(row + 1) * N3 + col]);
    Up[idx] = (unsigned)lo | ((unsigned)hi << 16);
}

// xp1 = x @ W1 + b_in (+ b_rec folded for z,r columns)   (K=15, memory-bound)
__global__ __launch_bounds__(256) void gemm_k15(
    const float* __restrict__ x, const float* __restrict__ W1,
    const float* __restrict__ bin, const float* __restrict__ brec,
    float* __restrict__ C) {
    __shared__ float xr[8][FF];
    const int m0 = blockIdx.x * 8;
    const int j  = blockIdx.y * 256 + threadIdx.x;
    if (threadIdx.x < 8 * FF) {
        int r = threadIdx.x / FF, k = threadIdx.x - r * FF;
        xr[r][k] = x[(size_t)(m0 + r) * FF + k];
    }
    __syncthreads();
    float wv[FF];
#pragma unroll
    for (int k = 0; k < FF; k++) wv[k] = W1[k * N3 + j];
    const float bj = bin[j] + (j < 2 * UU ? brec[j] : 0.f);
#pragma unroll
    for (int r = 0; r < 8; r++) {
        float a = bj;
#pragma unroll
        for (int k = 0; k < FF; k++) a += xr[r][k] * wv[k];
        C[(size_t)(m0 + r) * N3 + j] = a;
    }
}

// xp2 = seq1 @ W2 + b_in (+ b_rec folded for z,r)  via f16 MFMA.
__global__ __launch_bounds__(512) void gemm_xp_mfma(
    const _Float16* __restrict__ A, const uint4* __restrict__ Wp,
    const float* __restrict__ bin, const float* __restrict__ brec,
    float* __restrict__ C) {
    const int tid = threadIdx.x, w = tid >> 6, lane = tid & 63;
    const int mt = w >> 1;
    const int nb = (w & 1) * 24;
    const int arow = blockIdx.x * 64 + mt * 16 + (lane & 15);
    const int ko   = (lane >> 4) * 8;

    f32x4 acc[24] = {};
    const _Float16* ap = A + (size_t)arow * 256 + ko;

#pragma unroll
    for (int kt = 0; kt < 8; kt++) {
        half8 av = *(const half8*)(ap + kt * 32);
        const uint4* wp = Wp + (size_t)(nb * 8 + kt) * 64 + lane;
#pragma unroll
        for (int n = 0; n < 24; n++) {
            half8 bf = __builtin_bit_cast(half8, wp[(size_t)n * 8 * 64]);
            acc[n] = __builtin_amdgcn_mfma_f32_16x16x32_f16(av, bf, acc[n], 0, 0, 0);
        }
    }
    const int rbase = blockIdx.x * 64 + mt * 16 + (lane >> 4) * 4;
#pragma unroll
    for (int n = 0; n < 24; n++) {
        int col = (nb + n) * 16 + (lane & 15);
        float bv = bin[col] + (col < 2 * UU ? brec[col] : 0.f);
#pragma unroll
        for (int d = 0; d < 4; d++)
            C[(size_t)(rbase + d) * N3 + col] = acc[n][d] + bv;
    }
}

// ---------------- GRU recurrence: 16 waves x 3 n-tiles (EXACT r13) -----------
// One WG (1024 thr, 16 waves) per batch element. Wave w owns the z/r/hh tiles
// of units 16w..16w+15 (tiles w, 16+w, 32+w): ub = 24 half8 = 96 regs ->
// inside the 128-reg budget of 4 waves/SIMD (pinned). r14's tail-resequencing
// regressed 2030->3390 us/layer (MfmaUtil 16.4->9.7): ANY source-level
// reordering of this inner loop breaks the compiler's MFMA pipeline (same
// law as r10). The uniform 3-acc interleave below is a local optimum --
// scheduling-region edits are closed off.
__global__ __launch_bounds__(1024) __attribute__((amdgpu_waves_per_eu(4, 4)))
void gru_mfma16(const uint4* __restrict__ Up, const float* __restrict__ brec,
                const float* __restrict__ xp, _Float16* __restrict__ seq_out,
                float* __restrict__ state_out, float* __restrict__ extra_out) {
    const int b = blockIdx.x, tid = threadIdx.x;
    const int w = tid >> 6, lane = tid & 63;
    const int l15 = lane & 15;
    const int uA = 16 * w + l15;                   // this wave's unit range

    __shared__ __align__(16) _Float16 h2s[2][UU];

    // 24 B-fragments: z-tile w, r-tile 16+w, hh-tile 32+w, 8 k-tiles each
    half8 ub[24];
#pragma unroll
    for (int kt = 0; kt < 8; kt++) {
        ub[0 * 8 + kt] = __builtin_bit_cast(half8, Up[((w)      * 8 + kt) * 64 + lane]);
        ub[1 * 8 + kt] = __builtin_bit_cast(half8, Up[((16 + w) * 8 + kt) * 64 + lane]);
        ub[2 * 8 + kt] = __builtin_bit_cast(half8, Up[((32 + w) * 8 + kt) * 64 + lane]);
    }
    const float brh = brec[uA + 2 * UU];

    if (tid < 128) ((unsigned*)h2s[0])[tid] = 0u;
    float h = 0.f;
    __syncthreads();

    const float* __restrict__ xpb = xp + (size_t)b * TT * N3;
    float xz = xpb[uA], xr = xpb[uA + UU], xh = xpb[uA + 2 * UU];

    const int arow = (lane >> 4) << 3;

    for (int t = 0; t < TT; t++) {
        const float* xn = xpb + (size_t)(t + 1 < TT ? t + 1 : t) * N3;
        float xzn = xn[uA], xrn = xn[uA + UU], xhn = xn[uA + 2 * UU];

        const _Float16* hcur = h2s[t & 1];
        f32x4 a0 = {0.f, 0.f, 0.f, 0.f}, a1 = a0, a2 = a0;
#pragma unroll
        for (int kt = 0; kt < 8; kt++) {
            half8 av = *(const half8*)&hcur[kt * 32 + arow];
            a0 = __builtin_amdgcn_mfma_f32_16x16x32_f16(av, ub[0 * 8 + kt], a0, 0, 0, 0);
            a1 = __builtin_amdgcn_mfma_f32_16x16x32_f16(av, ub[1 * 8 + kt], a1, 0, 0, 0);
            a2 = __builtin_amdgcn_mfma_f32_16x16x32_f16(av, ub[2 * 8 + kt], a2, 0, 0, 0);
        }

        // gates (brz/brr pre-folded into xz/xr by the producer GEMM)
        float z  = 1.f / (1.f + __expf(-(xz + a0[0])));
        float r  = 1.f / (1.f + __expf(-(xr + a1[0])));
        float hh = xh + r * (a2[0] + brh);
        hh = hh > 0.f ? hh : 0.f;
        h = z * h + (1.f - z) * hh;

        _Float16* hnxt = h2s[(t + 1) & 1];
        if (lane < 16) {
            _Float16 hq = (_Float16)h;
            hnxt[uA] = hq;
            if (seq_out)
                seq_out[(size_t)b * TT * UU + (size_t)t * UU + uA] = hq;
        }
        __syncthreads();
        xz = xzn; xr = xrn; xh = xhn;
    }

    if (lane < 16) {
        state_out[b * UU + uA] = h;
        if (extra_out) extra_out[b * UU + uA] = h;
    }
}

extern "C" void kernel_launch(void* const* d_in, const int* in_sizes, int n_in,
                              void* d_out, int out_size, void* d_ws, size_t ws_size,
                              hipStream_t stream) {
    const float* x  = (const float*)d_in[0];
    const float* W1 = (const float*)d_in[1];
    const float* U1 = (const float*)d_in[2];
    const float* b1 = (const float*)d_in[3];
    const float* W2 = (const float*)d_in[4];
    const float* U2 = (const float*)d_in[5];
    const float* b2 = (const float*)d_in[6];
    float* out = (float*)d_out;

    uint4* U1p; hipGetSymbolAddress((void**)&U1p, HIP_SYMBOL(g_U1p));
    uint4* U2p; hipGetSymbolAddress((void**)&U2p, HIP_SYMBOL(g_U2p));
    uint4* W2p; hipGetSymbolAddress((void**)&W2p, HIP_SYMBOL(g_W2p));
    _Float16* seq1; hipGetSymbolAddress((void**)&seq1, HIP_SYMBOL(g_seq1));
    float* xp;      hipGetSymbolAddress((void**)&xp,   HIP_SYMBOL(g_xp));

    prep_upk<<<384, 256, 0, stream>>>(U1, (unsigned*)U1p);
    prep_upk<<<384, 256, 0, stream>>>(U2, (unsigned*)U2p);
    prep_upk<<<384, 256, 0, stream>>>(W2, (unsigned*)W2p);

    // layer 1 (b_rec z/r folded into xp by gemm_k15)
    gemm_k15<<<dim3(BB * TT / 8, 3), 256, 0, stream>>>(x, W1, b1, b1 + N3, xp);
    gru_mfma16<<<BB, 1024, 0, stream>>>(U1p, b1 + N3, xp, seq1, out + BB * UU, nullptr);

    // layer 2 (b_rec z/r folded into xp by gemm_xp_mfma)
    gemm_xp_mfma<<<BB * TT / 64, 512, 0, stream>>>(seq1, W2p, b2, b2 + N3, xp);
    gru_mfma16<<<BB, 1024, 0, stream>>>(U2p, b2 + N3, xp, nullptr, out + 2 * BB * UU, out);
}

// Round 16
// 4289.377 us; speedup vs baseline: 1.6109x; 1.0464x over previous
//
#include <hip/hip_runtime.h>

#define BB 64
#define TT 2048
#define FF 15
#define UU 256
#define N3 768

typedef _Float16 half8 __attribute__((ext_vector_type(8)));
typedef float f32x4 __attribute__((ext_vector_type(4)));

__device__ _Float16 g_seq1[BB * TT * UU];       // 67 MB (f16)
__device__ float g_xp[(size_t)BB * TT * N3];    // 402 MB (f32)
__device__ uint4 g_U1p[48 * 8 * 64];            // 48 n-tiles x 8 k-tiles x 64 lanes x 16B
__device__ uint4 g_U2p[48 * 8 * 64];
__device__ uint4 g_W2p[48 * 8 * 64];

// Pack a 256x768 fp32 matrix into per-lane MFMA B-fragments (f16).
// Fragment (nt, kt), lane l, dword d holds {M[kt*32+8*(l>>4)+2d][nt*16+(l&15)],
// M[...+2d+1][...]}. k-mapping f(l,i)=8*(l>>4)+i matches the A-side builds.
__global__ __launch_bounds__(256) void prep_upk(const float* __restrict__ U,
                                                unsigned* __restrict__ Up) {
    int idx = blockIdx.x * 256 + threadIdx.x;    // 0 .. 98303
    int d = idx & 3, l = (idx >> 2) & 63, kt = (idx >> 8) & 7, nt = idx >> 11;
    int row = kt * 32 + ((l >> 4) << 3) + 2 * d;
    int col = nt * 16 + (l & 15);
    unsigned short lo = __builtin_bit_cast(unsigned short, (_Float16)U[row * N3 + col]);
    unsigned short hi = __builtin_bit_cast(unsigned short, (_Float16)U[(row + 1) * N3 + col]);
    Up[idx] = (unsigned)lo | ((unsigned)hi << 16);
}

// xp1 = x @ W1 + b_in (+ b_rec folded for z,r columns)   (K=15, memory-bound)
__global__ __launch_bounds__(256) void gemm_k15(
    const float* __restrict__ x, const float* __restrict__ W1,
    const float* __restrict__ bin, const float* __restrict__ brec,
    float* __restrict__ C) {
    __shared__ float xr[8][FF];
    const int m0 = blockIdx.x * 8;
    const int j  = blockIdx.y * 256 + threadIdx.x;
    if (threadIdx.x < 8 * FF) {
        int r = threadIdx.x / FF, k = threadIdx.x - r * FF;
        xr[r][k] = x[(size_t)(m0 + r) * FF + k];
    }
    __syncthreads();
    float wv[FF];
#pragma unroll
    for (int k = 0; k < FF; k++) wv[k] = W1[k * N3 + j];
    const float bj = bin[j] + (j < 2 * UU ? brec[j] : 0.f);
#pragma unroll
    for (int r = 0; r < 8; r++) {
        float a = bj;
#pragma unroll
        for (int k = 0; k < FF; k++) a += xr[r][k] * wv[k];
        C[(size_t)(m0 + r) * N3 + j] = a;
    }
}

// xp2 = seq1 @ W2 + b_in (+ b_rec folded for z,r)  via f16 MFMA.
// r16 retile: 32-row blocks (4096), 8 waves; wave w -> m-tile (w&1),
// n-tiles (w>>1)*12..+11. acc shrinks 24->12 f32x4 (96->48 VGPRs) so
// occupancy roughly doubles -- the r15 profile showed this kernel memory-
// latency-bound at 2 blocks/CU (MfmaUtil 2.5, Occupancy 13.7) with its
// 104-VGPR accumulator footprint capping in-flight loads.
__global__ __launch_bounds__(512) void gemm_xp_mfma(
    const _Float16* __restrict__ A, const uint4* __restrict__ Wp,
    const float* __restrict__ bin, const float* __restrict__ brec,
    float* __restrict__ C) {
    const int tid = threadIdx.x, w = tid >> 6, lane = tid & 63;
    const int mt = w & 1;                        // 0..1
    const int nb = (w >> 1) * 12;                // n-tile base: 0,12,24,36
    const int arow = blockIdx.x * 32 + mt * 16 + (lane & 15);
    const int ko   = (lane >> 4) * 8;

    f32x4 acc[12] = {};
    const _Float16* ap = A + (size_t)arow * 256 + ko;

#pragma unroll
    for (int kt = 0; kt < 8; kt++) {
        half8 av = *(const half8*)(ap + kt * 32);
        const uint4* wp = Wp + (size_t)(nb * 8 + kt) * 64 + lane;
#pragma unroll
        for (int n = 0; n < 12; n++) {
            half8 bf = __builtin_bit_cast(half8, wp[(size_t)n * 8 * 64]);
            acc[n] = __builtin_amdgcn_mfma_f32_16x16x32_f16(av, bf, acc[n], 0, 0, 0);
        }
    }
    // D: col = lane&15, row-in-tile = (lane>>4)*4 + reg   (m89-verified)
    const int rbase = blockIdx.x * 32 + mt * 16 + (lane >> 4) * 4;
#pragma unroll
    for (int n = 0; n < 12; n++) {
        int col = (nb + n) * 16 + (lane & 15);
        float bv = bin[col] + (col < 2 * UU ? brec[col] : 0.f);
#pragma unroll
        for (int d = 0; d < 4; d++)
            C[(size_t)(rbase + d) * N3 + col] = acc[n][d] + bv;
    }
}

// ---------------- GRU recurrence: 16 waves x 3 n-tiles (EXACT r13) -----------
// One WG (1024 thr, 16 waves) per batch element. Wave w owns the z/r/hh tiles
// of units 16w..16w+15 (tiles w, 16+w, 32+w): ub = 24 half8 = 96 regs ->
// inside the 128-reg budget of 4 waves/SIMD (pinned). r14's tail-resequencing
// regressed 2030->3390 us/layer (MfmaUtil 16.4->9.7): ANY source-level
// reordering of this inner loop breaks the compiler's MFMA pipeline (same
// law as r10). The uniform 3-acc interleave below is a local optimum --
// scheduling-region edits are closed off.
__global__ __launch_bounds__(1024) __attribute__((amdgpu_waves_per_eu(4, 4)))
void gru_mfma16(const uint4* __restrict__ Up, const float* __restrict__ brec,
                const float* __restrict__ xp, _Float16* __restrict__ seq_out,
                float* __restrict__ state_out, float* __restrict__ extra_out) {
    const int b = blockIdx.x, tid = threadIdx.x;
    const int w = tid >> 6, lane = tid & 63;
    const int l15 = lane & 15;
    const int uA = 16 * w + l15;                   // this wave's unit range

    __shared__ __align__(16) _Float16 h2s[2][UU];

    // 24 B-fragments: z-tile w, r-tile 16+w, hh-tile 32+w, 8 k-tiles each
    half8 ub[24];
#pragma unroll
    for (int kt = 0; kt < 8; kt++) {
        ub[0 * 8 + kt] = __builtin_bit_cast(half8, Up[((w)      * 8 + kt) * 64 + lane]);
        ub[1 * 8 + kt] = __builtin_bit_cast(half8, Up[((16 + w) * 8 + kt) * 64 + lane]);
        ub[2 * 8 + kt] = __builtin_bit_cast(half8, Up[((32 + w) * 8 + kt) * 64 + lane]);
    }
    const float brh = brec[uA + 2 * UU];

    if (tid < 128) ((unsigned*)h2s[0])[tid] = 0u;
    float h = 0.f;
    __syncthreads();

    const float* __restrict__ xpb = xp + (size_t)b * TT * N3;
    float xz = xpb[uA], xr = xpb[uA + UU], xh = xpb[uA + 2 * UU];

    const int arow = (lane >> 4) << 3;

    for (int t = 0; t < TT; t++) {
        const float* xn = xpb + (size_t)(t + 1 < TT ? t + 1 : t) * N3;
        float xzn = xn[uA], xrn = xn[uA + UU], xhn = xn[uA + 2 * UU];

        const _Float16* hcur = h2s[t & 1];
        f32x4 a0 = {0.f, 0.f, 0.f, 0.f}, a1 = a0, a2 = a0;
#pragma unroll
        for (int kt = 0; kt < 8; kt++) {
            half8 av = *(const half8*)&hcur[kt * 32 + arow];
            a0 = __builtin_amdgcn_mfma_f32_16x16x32_f16(av, ub[0 * 8 + kt], a0, 0, 0, 0);
            a1 = __builtin_amdgcn_mfma_f32_16x16x32_f16(av, ub[1 * 8 + kt], a1, 0, 0, 0);
            a2 = __builtin_amdgcn_mfma_f32_16x16x32_f16(av, ub[2 * 8 + kt], a2, 0, 0, 0);
        }

        // gates (brz/brr pre-folded into xz/xr by the producer GEMM)
        float z  = 1.f / (1.f + __expf(-(xz + a0[0])));
        float r  = 1.f / (1.f + __expf(-(xr + a1[0])));
        float hh = xh + r * (a2[0] + brh);
        hh = hh > 0.f ? hh : 0.f;
        h = z * h + (1.f - z) * hh;

        _Float16* hnxt = h2s[(t + 1) & 1];
        if (lane < 16) {
            _Float16 hq = (_Float16)h;
            hnxt[uA] = hq;
            if (seq_out)
                seq_out[(size_t)b * TT * UU + (size_t)t * UU + uA] = hq;
        }
        __syncthreads();
        xz = xzn; xr = xrn; xh = xhn;
    }

    if (lane < 16) {
        state_out[b * UU + uA] = h;
        if (extra_out) extra_out[b * UU + uA] = h;
    }
}

extern "C" void kernel_launch(void* const* d_in, const int* in_sizes, int n_in,
                              void* d_out, int out_size, void* d_ws, size_t ws_size,
                              hipStream_t stream) {
    const float* x  = (const float*)d_in[0];
    const float* W1 = (const float*)d_in[1];
    const float* U1 = (const float*)d_in[2];
    const float* b1 = (const float*)d_in[3];
    const float* W2 = (const float*)d_in[4];
    const float* U2 = (const float*)d_in[5];
    const float* b2 = (const float*)d_in[6];
    float* out = (float*)d_out;

    uint4* U1p; hipGetSymbolAddress((void**)&U1p, HIP_SYMBOL(g_U1p));
    uint4* U2p; hipGetSymbolAddress((void**)&U2p, HIP_SYMBOL(g_U2p));
    uint4* W2p; hipGetSymbolAddress((void**)&W2p, HIP_SYMBOL(g_W2p));
    _Float16* seq1; hipGetSymbolAddress((void**)&seq1, HIP_SYMBOL(g_seq1));
    float* xp;      hipGetSymbolAddress((void**)&xp,   HIP_SYMBOL(g_xp));

    prep_upk<<<384, 256, 0, stream>>>(U1, (unsigned*)U1p);
    prep_upk<<<384, 256, 0, stream>>>(U2, (unsigned*)U2p);
    prep_upk<<<384, 256, 0, stream>>>(W2, (unsigned*)W2p);

    // layer 1 (b_rec z/r folded into xp by gemm_k15)
    gemm_k15<<<dim3(BB * TT / 8, 3), 256, 0, stream>>>(x, W1, b1, b1 + N3, xp);
    gru_mfma16<<<BB, 1024, 0, stream>>>(U1p, b1 + N3, xp, seq1, out + BB * UU, nullptr);

    // layer 2 (b_rec z/r folded into xp by gemm_xp_mfma)
    gemm_xp_mfma<<<BB * TT / 32, 512, 0, stream>>>(seq1, W2p, b2, b2 + N3, xp);
    gru_mfma16<<<BB, 1024, 0, stream>>>(U2p, b2 + N3, xp, nullptr, out + 2 * BB * UU, out);
}